// Round 2
// baseline (295.953 us; speedup 1.0000x reference)
//
#include <hip/hip_runtime.h>
#include <stdint.h>

#define OUT_F   4096
#define IN_F    11008
#define BATCH   64
#define NSUP    43                 // super-blocks per row (K-splits, 256 values each)
#define IPR     (IN_F / 2)         // 5504 ints per weight row
#define SB_ROW  (IN_F / 32)        // 344 sub-blocks per row

typedef __attribute__((ext_vector_type(8))) short  short8;
typedef __attribute__((ext_vector_type(4))) float  floatx4;
typedef __attribute__((ext_vector_type(4))) int    intx4;

__global__ __launch_bounds__(256) void init_out_kernel(const float* __restrict__ bias,
                                                       float* __restrict__ out) {
    int i = blockIdx.x * 256 + threadIdx.x;
    out[i] = bias[i & (OUT_F - 1)];
}

// pack two fp32 into two truncated bf16 in one v_perm
__device__ __forceinline__ unsigned pack_bf16(float f0, float f1) {
    return __builtin_amdgcn_perm(__float_as_uint(f1), __float_as_uint(f0), 0x07060302u);
}

// block = 64 output cols (4 tiles of 16) x 64 batch rows (4 waves x 16) x 256 K
// grid  = 64 col-blocks x 43 super-blocks = 2752
__global__ __launch_bounds__(256, 4) void qlin_kernel(
    const float* __restrict__ x,
    const int*   __restrict__ packed,
    const float* __restrict__ dd,
    const float* __restrict__ dmn_g,
    const int*   __restrict__ scales,
    const int*   __restrict__ mins,
    float*       __restrict__ out)
{
    const int sup = blockIdx.x % NSUP;     // super-block (K-chunk of 256)
    const int nb  = blockIdx.x / NSUP;     // output-column block 0..63
    const int wv  = threadIdx.x >> 6;      // M-tile 0..3
    const int ln  = threadIdx.x & 63;
    const int lo  = ln & 15;
    const int hi  = ln >> 4;               // k-quad 0..3

    // A operand: x[m][k], m = wv*16+lo, k = sup*256 + step*32 + hi*8 + j
    const int m = wv * 16 + lo;
    const float* aptr = x + (m * IN_F + sup * 256 + hi * 8);

    const int* bptr[4];
    float dk[4], dm[4], dmn[4];
    int scb[4];
    #pragma unroll
    for (int nt = 0; nt < 4; ++nt) {
        const int o = nb * 64 + nt * 16 + lo;        // weight row (output feature)
        bptr[nt] = packed + (o * IPR + sup * 128 + hi * 4);
        scb[nt]  = o * SB_ROW + sup * 8;             // first sub-block of this super-block
        const int s = o * NSUP + sup;
        const float dv = dd[s];
        dk[nt]  = dv * (1.0f / 945.0f);              // d/(63*15)
        dm[nt]  = dv * (1.0f / 63.0f);
        dmn[nt] = dmn_g[s];
    }

    floatx4 acc[4];
    #pragma unroll
    for (int nt = 0; nt < 4; ++nt) acc[nt] = (floatx4)0.0f;

    // two half-super-block groups of 4 sub-blocks each
    #pragma unroll 1
    for (int g = 0; g < 2; ++g) {
        // scales/mins for 4 consecutive sub-blocks: one intx4 each (16B aligned)
        intx4 scq[4], mnq[4];
        #pragma unroll
        for (int nt = 0; nt < 4; ++nt) {
            scq[nt] = *(const intx4*)(scales + scb[nt] + g * 4);
            mnq[nt] = *(const intx4*)(mins   + scb[nt] + g * 4);
        }

        #pragma unroll
        for (int s4 = 0; s4 < 4; ++s4) {
            const int step = g * 4 + s4;

            // ---- issue loads ----
            floatx4 a0 = *(const floatx4*)(aptr + step * 32);
            floatx4 a1 = *(const floatx4*)(aptr + step * 32 + 4);
            intx4 braw[4];
            #pragma unroll
            for (int nt = 0; nt < 4; ++nt)
                braw[nt] = *(const intx4*)(bptr[nt] + step * 16);

            // ---- A fragment: 8 fp32 -> 8 bf16 ----
            union { intx4 i; short8 s; } ua;
            ua.i.x = pack_bf16(a0.x, a0.y);
            ua.i.y = pack_bf16(a0.z, a0.w);
            ua.i.z = pack_bf16(a1.x, a1.y);
            ua.i.w = pack_bf16(a1.z, a1.w);
            short8 af = ua.s;

            // ---- B fragments: dequant + MFMA ----
            #pragma unroll
            for (int nt = 0; nt < 4; ++nt) {
                float A = dk[nt] * (float)scq[nt][s4];
                float B = fmaf(dm[nt], (float)mnq[nt][s4], dmn[nt]);
                union { intx4 i; short8 s; } uw;
                int v; float w0, w1;
                v = braw[nt].x;
                w0 = fmaf((float)(v & 15), A, B);
                w1 = fmaf((float)((v >> 4) & 15), A, B);
                uw.i.x = pack_bf16(w0, w1);
                v = braw[nt].y;
                w0 = fmaf((float)(v & 15), A, B);
                w1 = fmaf((float)((v >> 4) & 15), A, B);
                uw.i.y = pack_bf16(w0, w1);
                v = braw[nt].z;
                w0 = fmaf((float)(v & 15), A, B);
                w1 = fmaf((float)((v >> 4) & 15), A, B);
                uw.i.z = pack_bf16(w0, w1);
                v = braw[nt].w;
                w0 = fmaf((float)(v & 15), A, B);
                w1 = fmaf((float)((v >> 4) & 15), A, B);
                uw.i.w = pack_bf16(w0, w1);

                acc[nt] = __builtin_amdgcn_mfma_f32_16x16x32_bf16(af, uw.s, acc[nt], 0, 0, 0);
            }
        }
    }

    // ---- epilogue: C/D layout col=lane&15 (N), row=(lane>>4)*4+reg (M) ----
    #pragma unroll
    for (int nt = 0; nt < 4; ++nt) {
        const int col = nb * 64 + nt * 16 + lo;
        #pragma unroll
        for (int r = 0; r < 4; ++r) {
            const int row = wv * 16 + hi * 4 + r;
            atomicAdd(out + row * OUT_F + col, acc[nt][r]);
        }
    }
}

extern "C" void kernel_launch(void* const* d_in, const int* in_sizes, int n_in,
                              void* d_out, int out_size, void* d_ws, size_t ws_size,
                              hipStream_t stream) {
    (void)in_sizes; (void)n_in; (void)d_ws; (void)ws_size; (void)out_size;
    const float* x      = (const float*)d_in[0];
    const int*   packed = (const int*)d_in[1];
    const float* d      = (const float*)d_in[2];
    const float* dmin   = (const float*)d_in[3];
    const int*   scales = (const int*)d_in[4];
    const int*   mins   = (const int*)d_in[5];
    const float* bias   = (const float*)d_in[6];
    float* out = (float*)d_out;

    init_out_kernel<<<(BATCH * OUT_F) / 256, 256, 0, stream>>>(bias, out);
    qlin_kernel<<<64 * NSUP, 256, 0, stream>>>(x, packed, d, dmin, scales, mins, out);
}

// Round 3
// 183.408 us; speedup vs baseline: 1.6136x; 1.6136x over previous
//
#include <hip/hip_runtime.h>
#include <stdint.h>

#define OUT_F   4096
#define IN_F    11008
#define BATCH   64
#define NSUP    43                  // super-blocks per row
#define SB_ROW  344                 // sub-blocks per row
#define IPR     5504                // int32 elements per weight row (2 K-vals each)
#define NKS     16                  // K-splits
#define XP_BYTES   (4 * 344 * 64 * 16)              // 1,409,024 B  (x fragments)
#define PART_ELEMS ((size_t)NKS * BATCH * OUT_F)    // 4.19M floats
#define WS_FULL    (XP_BYTES + PART_ELEMS * 4)      // ~18.2 MB

typedef __attribute__((ext_vector_type(8))) short  short8;
typedef __attribute__((ext_vector_type(4))) float  floatx4;
typedef __attribute__((ext_vector_type(4))) int    intx4;

__device__ __forceinline__ unsigned pack_bf16(float f0, float f1) {
    // truncating fp32->bf16 pair pack (one v_perm)
    return __builtin_amdgcn_perm(__float_as_uint(f1), __float_as_uint(f0), 0x07060302u);
}

// ---- pre-pack x into MFMA A-fragment order: xp[mt][ksb][lane] = 8 bf16 (16B) ----
__global__ __launch_bounds__(256) void xprep_kernel(const float* __restrict__ x,
                                                    intx4* __restrict__ xp) {
    const int ksb = blockIdx.x;            // 0..343  (global sub-block = k/32)
    const int mt  = threadIdx.x >> 6;      // 0..3    (m-tile)
    const int l   = threadIdx.x & 63;
    const int lo  = l & 15, hi = l >> 4;
    const float* src = x + (mt * 16 + lo) * IN_F + ksb * 32 + hi * 8;
    floatx4 a0 = *(const floatx4*)src;
    floatx4 a1 = *(const floatx4*)(src + 4);
    intx4 r;
    r.x = pack_bf16(a0.x, a0.y);
    r.y = pack_bf16(a0.z, a0.w);
    r.z = pack_bf16(a1.x, a1.y);
    r.w = pack_bf16(a1.z, a1.w);
    xp[(mt * 344 + ksb) * 64 + l] = r;     // lane-contiguous: coalesced store
}

__global__ __launch_bounds__(256) void init_out_kernel(const float* __restrict__ bias,
                                                       float* __restrict__ out) {
    int i = blockIdx.x * 256 + threadIdx.x;
    out[i] = bias[i & (OUT_F - 1)];
}

__global__ __launch_bounds__(256) void reduce_kernel(const float* __restrict__ part,
                                                     const float* __restrict__ bias,
                                                     float* __restrict__ out) {
    const int i = blockIdx.x * 256 + threadIdx.x;   // 0..262143
    float s = bias[i & (OUT_F - 1)];
    #pragma unroll
    for (int k = 0; k < NKS; ++k) s += part[(size_t)k * (BATCH * OUT_F) + i];
    out[i] = s;
}

// block: 64 out-features (wave w owns 16) x 64 batch rows (4 m-tiles per wave) x K-split
// grid: 64 nb x 16 ks = 1024 blocks
template<bool USE_XP, bool USE_PART>
__global__ __launch_bounds__(256, 4) void qlin_main(
    const float* __restrict__ x,
    const intx4* __restrict__ xp,
    const int*   __restrict__ packed,
    const float* __restrict__ dd,
    const float* __restrict__ dmn_g,
    const int*   __restrict__ scales,
    const int*   __restrict__ mins,
    float*       __restrict__ part,
    float*       __restrict__ out)
{
    const int nb = blockIdx.x & 63;
    const int ks = blockIdx.x >> 6;        // 0..15
    const int w  = threadIdx.x >> 6;       // wave -> n-tile
    const int l  = threadIdx.x & 63;
    const int lo = l & 15, hi = l >> 4;

    const int o = nb * 64 + w * 16 + lo;   // this lane's out-feature (B-fragment row)
    const int sup0 = ks < 11 ? 3 * ks : 33 + 2 * (ks - 11);
    const int nsup = ks < 11 ? 3 : 2;

    floatx4 acc[4];
    #pragma unroll
    for (int mt = 0; mt < 4; ++mt) acc[mt] = (floatx4)0.0f;

    #pragma unroll 1
    for (int s = 0; s < nsup; ++s) {
        const int sup = sup0 + s;

        // per-sup, per-lane dequant constants (registers, no LDS, no barrier)
        const int sci = o * SB_ROW + sup * 8;
        intx4 sc0 = *(const intx4*)(scales + sci);
        intx4 sc1 = *(const intx4*)(scales + sci + 4);
        intx4 mn0 = *(const intx4*)(mins + sci);
        intx4 mn1 = *(const intx4*)(mins + sci + 4);
        const float dv   = dd[o * NSUP + sup];
        const float dmnv = dmn_g[o * NSUP + sup];
        const float d945 = dv * (1.0f / 945.0f);   // d/(63*15)
        const float d63  = dv * (1.0f / 63.0f);

        const int* bp = packed + o * IPR + sup * 128 + hi * 4;
        const intx4* xpp = xp + (sup * 8) * 64 + l;

        #pragma unroll
        for (int step = 0; step < 8; ++step) {
            // B raw: 16B per lane, distinct per wave (16 rows x 64B: minimal scatter)
            intx4 braw = *(const intx4*)(bp + step * 16);

            // A fragments for the 4 m-tiles
            intx4 xf[4];
            if (USE_XP) {
                #pragma unroll
                for (int mt = 0; mt < 4; ++mt)
                    xf[mt] = xpp[(mt * 344 + step) * 64];   // coalesced, L1-shared
            } else {
                #pragma unroll
                for (int mt = 0; mt < 4; ++mt) {
                    const float* src = x + (mt * 16 + lo) * IN_F + sup * 256 + step * 32 + hi * 8;
                    floatx4 a0 = *(const floatx4*)src;
                    floatx4 a1 = *(const floatx4*)(src + 4);
                    xf[mt].x = pack_bf16(a0.x, a0.y);
                    xf[mt].y = pack_bf16(a0.z, a0.w);
                    xf[mt].z = pack_bf16(a1.x, a1.y);
                    xf[mt].w = pack_bf16(a1.z, a1.w);
                }
            }

            const int sc = (step < 4) ? sc0[step & 3] : sc1[step & 3];
            const int mn = (step < 4) ? mn0[step & 3] : mn1[step & 3];
            const float A = d945 * (float)sc;
            const float B = fmaf(d63, (float)mn, dmnv);

            // dequant 4 ints (8 nibbles; each int holds one byte, so v>>4 <= 15)
            union { intx4 i; short8 s; } uw;
            {
                const int v0 = braw.x, v1 = braw.y, v2 = braw.z, v3 = braw.w;
                uw.i.x = pack_bf16(fmaf((float)(v0 & 15), A, B), fmaf((float)(v0 >> 4), A, B));
                uw.i.y = pack_bf16(fmaf((float)(v1 & 15), A, B), fmaf((float)(v1 >> 4), A, B));
                uw.i.z = pack_bf16(fmaf((float)(v2 & 15), A, B), fmaf((float)(v2 >> 4), A, B));
                uw.i.w = pack_bf16(fmaf((float)(v3 & 15), A, B), fmaf((float)(v3 >> 4), A, B));
            }

            union { intx4 i; short8 s; } ua0, ua1, ua2, ua3;
            ua0.i = xf[0]; ua1.i = xf[1]; ua2.i = xf[2]; ua3.i = xf[3];
            acc[0] = __builtin_amdgcn_mfma_f32_16x16x32_bf16(ua0.s, uw.s, acc[0], 0, 0, 0);
            acc[1] = __builtin_amdgcn_mfma_f32_16x16x32_bf16(ua1.s, uw.s, acc[1], 0, 0, 0);
            acc[2] = __builtin_amdgcn_mfma_f32_16x16x32_bf16(ua2.s, uw.s, acc[2], 0, 0, 0);
            acc[3] = __builtin_amdgcn_mfma_f32_16x16x32_bf16(ua3.s, uw.s, acc[3], 0, 0, 0);
        }
    }

    // epilogue: D col = lane&15 = n (out-feature o), row = hi*4+r = m within tile
    if (USE_PART) {
        float* pbase = part + (size_t)ks * (BATCH * OUT_F) + o;
        #pragma unroll
        for (int mt = 0; mt < 4; ++mt) {
            #pragma unroll
            for (int r = 0; r < 4; ++r)
                pbase[(mt * 16 + hi * 4 + r) * OUT_F] = acc[mt][r];
        }
    } else {
        #pragma unroll
        for (int mt = 0; mt < 4; ++mt) {
            #pragma unroll
            for (int r = 0; r < 4; ++r)
                atomicAdd(out + (mt * 16 + hi * 4 + r) * OUT_F + o, acc[mt][r]);
        }
    }
}

extern "C" void kernel_launch(void* const* d_in, const int* in_sizes, int n_in,
                              void* d_out, int out_size, void* d_ws, size_t ws_size,
                              hipStream_t stream) {
    (void)in_sizes; (void)n_in; (void)out_size;
    const float* x      = (const float*)d_in[0];
    const int*   packed = (const int*)d_in[1];
    const float* d      = (const float*)d_in[2];
    const float* dmin   = (const float*)d_in[3];
    const int*   scales = (const int*)d_in[4];
    const int*   mins   = (const int*)d_in[5];
    const float* bias   = (const float*)d_in[6];
    float* out = (float*)d_out;

    const bool has_xp   = ws_size >= (size_t)XP_BYTES;
    const bool has_part = ws_size >= (size_t)WS_FULL;
    intx4* xp   = (intx4*)d_ws;
    float* part = (float*)((char*)d_ws + XP_BYTES);

    if (has_xp)
        xprep_kernel<<<344, 256, 0, stream>>>(x, xp);

    if (has_part) {
        qlin_main<true, true><<<64 * NKS, 256, 0, stream>>>(
            x, xp, packed, d, dmin, scales, mins, part, out);
        reduce_kernel<<<(BATCH * OUT_F) / 256, 256, 0, stream>>>(part, bias, out);
    } else {
        init_out_kernel<<<(BATCH * OUT_F) / 256, 256, 0, stream>>>(bias, out);
        if (has_xp)
            qlin_main<true, false><<<64 * NKS, 256, 0, stream>>>(
                x, xp, packed, d, dmin, scales, mins, part, out);
        else
            qlin_main<false, false><<<64 * NKS, 256, 0, stream>>>(
                x, xp, packed, d, dmin, scales, mins, part, out);
    }
}

// Round 4
// 181.549 us; speedup vs baseline: 1.6302x; 1.0102x over previous
//
#include <hip/hip_runtime.h>
#include <stdint.h>

#define OUT_F   4096
#define IN_F    11008
#define BATCH   64
#define NSUP    43                  // super-blocks per row
#define SB_ROW  344                 // sub-blocks per row
#define IPR     5504                // int32 elements per weight row
#define NKS     16                  // K-splits
#define XP_BYTES   (4 * 344 * 64 * 16)              // 1,409,024 B
#define PART_ELEMS ((size_t)NKS * BATCH * OUT_F)
#define WS_FULL    (XP_BYTES + PART_ELEMS * 4)

typedef __attribute__((ext_vector_type(8))) short  short8;
typedef __attribute__((ext_vector_type(4))) float  floatx4;
typedef __attribute__((ext_vector_type(4))) int    intx4;

__device__ __forceinline__ unsigned pack_bf16(float f0, float f1) {
    return __builtin_amdgcn_perm(__float_as_uint(f1), __float_as_uint(f0), 0x07060302u);
}

// ---- pre-pack x into MFMA A-fragment order ----
__global__ __launch_bounds__(256) void xprep_kernel(const float* __restrict__ x,
                                                    intx4* __restrict__ xp) {
    const int ksb = blockIdx.x;            // 0..343
    const int mt  = threadIdx.x >> 6;
    const int l   = threadIdx.x & 63;
    const int lo  = l & 15, hi = l >> 4;
    const float* src = x + (mt * 16 + lo) * IN_F + ksb * 32 + hi * 8;
    floatx4 a0 = *(const floatx4*)src;
    floatx4 a1 = *(const floatx4*)(src + 4);
    intx4 r;
    r.x = pack_bf16(a0.x, a0.y);
    r.y = pack_bf16(a0.z, a0.w);
    r.z = pack_bf16(a1.x, a1.y);
    r.w = pack_bf16(a1.z, a1.w);
    xp[(mt * 344 + ksb) * 64 + l] = r;
}

__global__ __launch_bounds__(256) void init_out_kernel(const float* __restrict__ bias,
                                                       float* __restrict__ out) {
    int i = blockIdx.x * 256 + threadIdx.x;
    out[i] = bias[i & (OUT_F - 1)];
}

__global__ __launch_bounds__(256) void reduce_kernel(const float* __restrict__ part,
                                                     const float* __restrict__ bias,
                                                     float* __restrict__ out) {
    const int i = blockIdx.x * 256 + threadIdx.x;
    float s = bias[i & (OUT_F - 1)];
    #pragma unroll
    for (int k = 0; k < NKS; ++k) s += part[(size_t)k * (BATCH * OUT_F) + i];
    out[i] = s;
}

// block: 64 out-features x 64 batch rows; explicit half-super-block prefetch pipeline
template<bool USE_PART>
__global__ __launch_bounds__(256, 4) void qlin_main(
    const intx4* __restrict__ xp,
    const int*   __restrict__ packed,
    const float* __restrict__ dd,
    const float* __restrict__ dmn_g,
    const int*   __restrict__ scales,
    const int*   __restrict__ mins,
    float*       __restrict__ part,
    float*       __restrict__ out)
{
    const int ks = blockIdx.x & 15;        // low bits: mix 2-sup/3-sup blocks per CU
    const int nb = blockIdx.x >> 4;
    const int w  = threadIdx.x >> 6;
    const int l  = threadIdx.x & 63;
    const int lo = l & 15, hi = l >> 4;

    const int o    = nb * 64 + w * 16 + lo;
    const int sup0 = ks < 11 ? 3 * ks : 33 + 2 * (ks - 11);
    const int nsup = ks < 11 ? 3 : 2;

    floatx4 acc[4];
    #pragma unroll
    for (int mt = 0; mt < 4; ++mt) acc[mt] = (floatx4)0.0f;

    const int* bp  = packed + o * IPR + sup0 * 128 + hi * 4;
    const int* scp = scales + o * SB_ROW + sup0 * 8;
    const int* mnp = mins   + o * SB_ROW + sup0 * 8;
    int didx = o * NSUP + sup0;
    const intx4* xpc = xp + (sup0 * 8) * 64 + l;

    intx4 bc[4], bn[4], scc, mnc, scn, mnn;
    #pragma unroll
    for (int i = 0; i < 4; ++i)
        bc[i] = __builtin_nontemporal_load((const intx4*)(bp + i * 16));
    scc = *(const intx4*)scp;
    mnc = *(const intx4*)mnp;
    float dvc = dd[didx], dmc = dmn_g[didx];

    auto do_half = [&](const intx4* bb, intx4 scv, intx4 mnv,
                       float A945, float A63, float ADMN, const intx4* xq) {
        #pragma unroll
        for (int st = 0; st < 4; ++st) {
            const int v0 = bb[st].x, v1 = bb[st].y, v2 = bb[st].z, v3 = bb[st].w;
            const float A = A945 * (float)scv[st];
            const float B = fmaf(A63, (float)mnv[st], ADMN);
            union { intx4 i; short8 s; } uw;
            uw.i.x = pack_bf16(fmaf((float)(v0 & 15), A, B), fmaf((float)(v0 >> 4), A, B));
            uw.i.y = pack_bf16(fmaf((float)(v1 & 15), A, B), fmaf((float)(v1 >> 4), A, B));
            uw.i.z = pack_bf16(fmaf((float)(v2 & 15), A, B), fmaf((float)(v2 >> 4), A, B));
            uw.i.w = pack_bf16(fmaf((float)(v3 & 15), A, B), fmaf((float)(v3 >> 4), A, B));
            union { intx4 i; short8 s; } u0, u1, u2, u3;
            u0.i = xq[(0 * 344 + st) * 64];
            u1.i = xq[(1 * 344 + st) * 64];
            u2.i = xq[(2 * 344 + st) * 64];
            u3.i = xq[(3 * 344 + st) * 64];
            acc[0] = __builtin_amdgcn_mfma_f32_16x16x32_bf16(u0.s, uw.s, acc[0], 0, 0, 0);
            acc[1] = __builtin_amdgcn_mfma_f32_16x16x32_bf16(u1.s, uw.s, acc[1], 0, 0, 0);
            acc[2] = __builtin_amdgcn_mfma_f32_16x16x32_bf16(u2.s, uw.s, acc[2], 0, 0, 0);
            acc[3] = __builtin_amdgcn_mfma_f32_16x16x32_bf16(u3.s, uw.s, acc[3], 0, 0, 0);
        }
    };

    #pragma unroll 1
    for (int s = 0;; ++s) {
        const bool last = (s == nsup - 1);
        // prefetch half g=1 of current sup
        #pragma unroll
        for (int i = 0; i < 4; ++i)
            bn[i] = __builtin_nontemporal_load((const intx4*)(bp + 64 + i * 16));
        scn = *(const intx4*)(scp + 4);
        mnn = *(const intx4*)(mnp + 4);

        const float A945 = dvc * (1.0f / 945.0f);
        const float A63  = dvc * (1.0f / 63.0f);
        do_half(bc, scc, mnc, A945, A63, dmc, xpc);

        // prefetch half g=0 of next sup (while computing g=1)
        float dvn = 0.0f, dmnn = 0.0f;
        if (!last) {
            #pragma unroll
            for (int i = 0; i < 4; ++i)
                bc[i] = __builtin_nontemporal_load((const intx4*)(bp + 128 + i * 16));
            scc = *(const intx4*)(scp + 8);
            mnc = *(const intx4*)(mnp + 8);
            dvn = dd[didx + 1];
            dmnn = dmn_g[didx + 1];
        }
        do_half(bn, scn, mnn, A945, A63, dmc, xpc + 256);
        if (last) break;
        dvc = dvn; dmc = dmnn; ++didx;
        bp += 128; scp += 8; mnp += 8; xpc += 512;
    }

    // epilogue: D col = lane&15 = n, row = hi*4+r = m within tile
    if (USE_PART) {
        float* pbase = part + (size_t)ks * (BATCH * OUT_F) + o;
        #pragma unroll
        for (int mt = 0; mt < 4; ++mt) {
            #pragma unroll
            for (int r = 0; r < 4; ++r)
                pbase[(mt * 16 + hi * 4 + r) * OUT_F] = acc[mt][r];
        }
    } else {
        #pragma unroll
        for (int mt = 0; mt < 4; ++mt) {
            #pragma unroll
            for (int r = 0; r < 4; ++r)
                atomicAdd(out + (mt * 16 + hi * 4 + r) * OUT_F + o, acc[mt][r]);
        }
    }
}

extern "C" void kernel_launch(void* const* d_in, const int* in_sizes, int n_in,
                              void* d_out, int out_size, void* d_ws, size_t ws_size,
                              hipStream_t stream) {
    (void)in_sizes; (void)n_in; (void)out_size;
    const float* x      = (const float*)d_in[0];
    const int*   packed = (const int*)d_in[1];
    const float* d      = (const float*)d_in[2];
    const float* dmin   = (const float*)d_in[3];
    const int*   scales = (const int*)d_in[4];
    const int*   mins   = (const int*)d_in[5];
    const float* bias   = (const float*)d_in[6];
    float* out = (float*)d_out;

    const bool has_part = ws_size >= (size_t)WS_FULL;
    intx4* xp   = (intx4*)d_ws;
    float* part = (float*)((char*)d_ws + XP_BYTES);

    xprep_kernel<<<344, 256, 0, stream>>>(x, xp);

    if (has_part) {
        qlin_main<true><<<64 * NKS, 256, 0, stream>>>(
            xp, packed, d, dmin, scales, mins, part, out);
        reduce_kernel<<<(BATCH * OUT_F) / 256, 256, 0, stream>>>(part, bias, out);
    } else {
        init_out_kernel<<<(BATCH * OUT_F) / 256, 256, 0, stream>>>(bias, out);
        qlin_main<false><<<64 * NKS, 256, 0, stream>>>(
            xp, packed, d, dmin, scales, mins, part, out);
    }
}

// Round 5
// 181.348 us; speedup vs baseline: 1.6320x; 1.0011x over previous
//
#include <hip/hip_runtime.h>
#include <stdint.h>

#define OUT_F   4096
#define IN_F    11008
#define BATCH   64
#define NSUP    43                  // super-blocks per row
#define SB_ROW  344                 // sub-blocks per row
#define IPR     5504                // int32 elements per weight row
#define NKS     16                  // K-splits
#define XP_BYTES   (4 * 344 * 64 * 16)              // 1,409,024 B
#define PART_ELEMS ((size_t)NKS * BATCH * OUT_F)
#define WS_FULL    (XP_BYTES + PART_ELEMS * 4)

typedef __attribute__((ext_vector_type(8))) short  short8;
typedef __attribute__((ext_vector_type(4))) float  floatx4;
typedef __attribute__((ext_vector_type(4))) int    intx4;

__device__ __forceinline__ unsigned pack_bf16(float f0, float f1) {
    return __builtin_amdgcn_perm(__float_as_uint(f1), __float_as_uint(f0), 0x07060302u);
}

// ---- pre-pack x into MFMA A-fragment order ----
__global__ __launch_bounds__(256) void xprep_kernel(const float* __restrict__ x,
                                                    intx4* __restrict__ xp) {
    const int ksb = blockIdx.x;            // 0..343
    const int mt  = threadIdx.x >> 6;
    const int l   = threadIdx.x & 63;
    const int lo  = l & 15, hi = l >> 4;
    const float* src = x + (mt * 16 + lo) * IN_F + ksb * 32 + hi * 8;
    floatx4 a0 = *(const floatx4*)src;
    floatx4 a1 = *(const floatx4*)(src + 4);
    intx4 r;
    r.x = pack_bf16(a0.x, a0.y);
    r.y = pack_bf16(a0.z, a0.w);
    r.z = pack_bf16(a1.x, a1.y);
    r.w = pack_bf16(a1.z, a1.w);
    xp[(mt * 344 + ksb) * 64 + l] = r;
}

__global__ __launch_bounds__(256) void init_out_kernel(const float* __restrict__ bias,
                                                       float* __restrict__ out) {
    int i = blockIdx.x * 256 + threadIdx.x;
    out[i] = bias[i & (OUT_F - 1)];
}

__global__ __launch_bounds__(256) void reduce_kernel(const float* __restrict__ part,
                                                     const float* __restrict__ bias,
                                                     float* __restrict__ out) {
    const int i = blockIdx.x * 256 + threadIdx.x;
    float s = bias[i & (OUT_F - 1)];
    #pragma unroll
    for (int k = 0; k < NKS; ++k) s += part[(size_t)k * (BATCH * OUT_F) + i];
    out[i] = s;
}

// block: 64 out-features x 64 batch rows x K-split.
// Per super-block: batch-issue ALL loads (8 braw + 32 xf + scales), one wait, compute.
template<bool USE_PART>
__global__ __launch_bounds__(256, 2) void qlin_main(
    const intx4* __restrict__ xp,
    const int*   __restrict__ packed,
    const float* __restrict__ dd,
    const float* __restrict__ dmn_g,
    const int*   __restrict__ scales,
    const int*   __restrict__ mins,
    float*       __restrict__ part,
    float*       __restrict__ out)
{
    const int ks = blockIdx.x & 15;        // low bits: mix 2-sup/3-sup blocks per CU
    const int nb = blockIdx.x >> 4;
    const int w  = threadIdx.x >> 6;
    const int l  = threadIdx.x & 63;
    const int lo = l & 15, hi = l >> 4;

    const int o    = nb * 64 + w * 16 + lo;
    const int sup0 = ks < 11 ? 3 * ks : 33 + 2 * (ks - 11);
    const int nsup = ks < 11 ? 3 : 2;

    const int*   bp0  = packed + o * IPR + sup0 * 128 + hi * 4;
    const intx4* xq0  = xp + (sup0 * 8) * 64 + l;
    const int*   scp0 = scales + o * SB_ROW + sup0 * 8;
    const int*   mnp0 = mins   + o * SB_ROW + sup0 * 8;
    const int    didx0 = o * NSUP + sup0;

    floatx4 acc[4];
    #pragma unroll
    for (int mt = 0; mt < 4; ++mt) acc[mt] = (floatx4)0.0f;

    #pragma unroll 1
    for (int s = 0; s < nsup; ++s) {
        const int*   bp = bp0 + s * 128;
        const intx4* xq = xq0 + s * 512;

        // ---- batch-issue every load for this super-block ----
        intx4 br[8];
        #pragma unroll
        for (int st = 0; st < 8; ++st)
            br[st] = __builtin_nontemporal_load((const intx4*)(bp + st * 16));

        intx4 xf[32];
        #pragma unroll
        for (int mt = 0; mt < 4; ++mt) {
            #pragma unroll
            for (int st = 0; st < 8; ++st)
                xf[mt * 8 + st] = xq[(mt * 344 + st) * 64];
        }

        const intx4 sc0 = *(const intx4*)(scp0 + s * 8);
        const intx4 sc1 = *(const intx4*)(scp0 + s * 8 + 4);
        const intx4 mn0 = *(const intx4*)(mnp0 + s * 8);
        const intx4 mn1 = *(const intx4*)(mnp0 + s * 8 + 4);
        const float dv  = dd[didx0 + s];
        const float dmv = dmn_g[didx0 + s];
        const float A945 = dv * (1.0f / 945.0f);   // d/(63*15)
        const float A63  = dv * (1.0f / 63.0f);

        // ---- compute 8 steps, no further memory waits ----
        #pragma unroll
        for (int st = 0; st < 8; ++st) {
            const int scv = (st < 4) ? sc0[st & 3] : sc1[st & 3];
            const int mnv = (st < 4) ? mn0[st & 3] : mn1[st & 3];
            const float A = A945 * (float)scv;
            const float B = fmaf(A63, (float)mnv, dmv);
            const int v0 = br[st].x, v1 = br[st].y, v2 = br[st].z, v3 = br[st].w;
            union { intx4 i; short8 s8; } uw;
            uw.i.x = pack_bf16(fmaf((float)(v0 & 15), A, B), fmaf((float)(v0 >> 4), A, B));
            uw.i.y = pack_bf16(fmaf((float)(v1 & 15), A, B), fmaf((float)(v1 >> 4), A, B));
            uw.i.z = pack_bf16(fmaf((float)(v2 & 15), A, B), fmaf((float)(v2 >> 4), A, B));
            uw.i.w = pack_bf16(fmaf((float)(v3 & 15), A, B), fmaf((float)(v3 >> 4), A, B));

            union { intx4 i; short8 s8; } u0, u1, u2, u3;
            u0.i = xf[0 * 8 + st];
            u1.i = xf[1 * 8 + st];
            u2.i = xf[2 * 8 + st];
            u3.i = xf[3 * 8 + st];
            acc[0] = __builtin_amdgcn_mfma_f32_16x16x32_bf16(u0.s8, uw.s8, acc[0], 0, 0, 0);
            acc[1] = __builtin_amdgcn_mfma_f32_16x16x32_bf16(u1.s8, uw.s8, acc[1], 0, 0, 0);
            acc[2] = __builtin_amdgcn_mfma_f32_16x16x32_bf16(u2.s8, uw.s8, acc[2], 0, 0, 0);
            acc[3] = __builtin_amdgcn_mfma_f32_16x16x32_bf16(u3.s8, uw.s8, acc[3], 0, 0, 0);
        }
    }

    // epilogue: D col = lane&15 = n (out-feature o), row = hi*4+r = m within tile
    if (USE_PART) {
        float* pbase = part + (size_t)ks * (BATCH * OUT_F) + o;
        #pragma unroll
        for (int mt = 0; mt < 4; ++mt) {
            #pragma unroll
            for (int r = 0; r < 4; ++r)
                pbase[(mt * 16 + hi * 4 + r) * OUT_F] = acc[mt][r];
        }
    } else {
        #pragma unroll
        for (int mt = 0; mt < 4; ++mt) {
            #pragma unroll
            for (int r = 0; r < 4; ++r)
                atomicAdd(out + (mt * 16 + hi * 4 + r) * OUT_F + o, acc[mt][r]);
        }
    }
}

extern "C" void kernel_launch(void* const* d_in, const int* in_sizes, int n_in,
                              void* d_out, int out_size, void* d_ws, size_t ws_size,
                              hipStream_t stream) {
    (void)in_sizes; (void)n_in; (void)out_size;
    const float* x      = (const float*)d_in[0];
    const int*   packed = (const int*)d_in[1];
    const float* d      = (const float*)d_in[2];
    const float* dmin   = (const float*)d_in[3];
    const int*   scales = (const int*)d_in[4];
    const int*   mins   = (const int*)d_in[5];
    const float* bias   = (const float*)d_in[6];
    float* out = (float*)d_out;

    const bool has_part = ws_size >= (size_t)WS_FULL;
    intx4* xp   = (intx4*)d_ws;
    float* part = (float*)((char*)d_ws + XP_BYTES);

    xprep_kernel<<<344, 256, 0, stream>>>(x, xp);

    if (has_part) {
        qlin_main<true><<<64 * NKS, 256, 0, stream>>>(
            xp, packed, d, dmin, scales, mins, part, out);
        reduce_kernel<<<(BATCH * OUT_F) / 256, 256, 0, stream>>>(part, bias, out);
    } else {
        init_out_kernel<<<(BATCH * OUT_F) / 256, 256, 0, stream>>>(bias, out);
        qlin_main<false><<<64 * NKS, 256, 0, stream>>>(
            xp, packed, d, dmin, scales, mins, part, out);
    }
}

// Round 6
// 167.652 us; speedup vs baseline: 1.7653x; 1.0817x over previous
//
#include <hip/hip_runtime.h>
#include <stdint.h>

#define OUT_F   4096
#define IN_F    11008
#define BATCH   64
#define NSUP    43                  // super-blocks per row
#define SB_ROW  344                 // sub-blocks per row
#define IPR     5504                // int32 elements per weight row
#define NKS     12                  // K-splits -> 64 x 12 = 768 blocks = 3/CU exactly
#define XP_BYTES   (4 * 344 * 64 * 16)              // 1,409,024 B
#define PART_ELEMS ((size_t)NKS * BATCH * OUT_F)
#define WS_FULL    (XP_BYTES + PART_ELEMS * 4)

typedef __attribute__((ext_vector_type(8))) short  short8;
typedef __attribute__((ext_vector_type(4))) float  floatx4;
typedef __attribute__((ext_vector_type(4))) int    intx4;

__device__ __forceinline__ unsigned pack_bf16(float f0, float f1) {
    return __builtin_amdgcn_perm(__float_as_uint(f1), __float_as_uint(f0), 0x07060302u);
}

// ---- pre-pack x into MFMA A-fragment order: xp[(mt*344 + ksb)*64 + l] ----
__global__ __launch_bounds__(256) void xprep_kernel(const float* __restrict__ x,
                                                    intx4* __restrict__ xp) {
    const int ksb = blockIdx.x;            // 0..343
    const int mt  = threadIdx.x >> 6;
    const int l   = threadIdx.x & 63;
    const int lo  = l & 15, hi = l >> 4;
    const float* src = x + (mt * 16 + lo) * IN_F + ksb * 32 + hi * 8;
    floatx4 a0 = *(const floatx4*)src;
    floatx4 a1 = *(const floatx4*)(src + 4);
    intx4 r;
    r.x = pack_bf16(a0.x, a0.y);
    r.y = pack_bf16(a0.z, a0.w);
    r.z = pack_bf16(a1.x, a1.y);
    r.w = pack_bf16(a1.z, a1.w);
    xp[(mt * 344 + ksb) * 64 + l] = r;
}

__global__ __launch_bounds__(256) void init_out_kernel(const float* __restrict__ bias,
                                                       float* __restrict__ out) {
    int i = blockIdx.x * 256 + threadIdx.x;
    out[i] = bias[i & (OUT_F - 1)];
}

__global__ __launch_bounds__(256) void reduce_kernel(const float* __restrict__ part,
                                                     const float* __restrict__ bias,
                                                     float* __restrict__ out) {
    const int i = blockIdx.x * 256 + threadIdx.x;
    float s = bias[i & (OUT_F - 1)];
    #pragma unroll
    for (int k = 0; k < NKS; ++k) s += part[(size_t)k * (BATCH * OUT_F) + i];
    out[i] = s;
}

// block = 64 out-features x 64 batch rows. Per super-block: stage xf/scales/d in
// LDS ONCE (kills the 4x intra-block L1 redundancy), braw stays per-wave regs.
template<bool USE_PART>
__global__ __launch_bounds__(256, 3) void qlin_main(
    const intx4* __restrict__ xp,
    const int*   __restrict__ packed,
    const float* __restrict__ dd,
    const float* __restrict__ dmn_g,
    const int*   __restrict__ scales,
    const int*   __restrict__ mins,
    float*       __restrict__ part,
    float*       __restrict__ out)
{
    __shared__ intx4 xfs[2048];     // 32KB  [mt*512 + st*64 + l]
    __shared__ int   scs[512];      // 2KB   [r*8 + j]
    __shared__ int   mns[512];      // 2KB
    __shared__ float dsx[64];       // per-row d
    __shared__ float dmx[64];       // per-row dmin

    const int nb  = blockIdx.x & 63;
    const int ks  = blockIdx.x >> 6;          // 0..11
    const int tid = threadIdx.x;
    const int w   = tid >> 6;
    const int l   = tid & 63;
    const int lo  = l & 15, hi = l >> 4;

    const int o    = nb * 64 + w * 16 + lo;   // lane's out-feature
    const int r    = w * 16 + lo;             // row within block
    const int sup0 = ks < 7 ? 4 * ks : 28 + 3 * (ks - 7);
    const int nsup = ks < 7 ? 4 : 3;

    floatx4 acc[4];
    #pragma unroll
    for (int mt = 0; mt < 4; ++mt) acc[mt] = (floatx4)0.0f;

    const int* bp0 = packed + o * IPR + sup0 * 128 + hi * 4;
    const int tr = tid & 63;                  // staging row for this thread
    const int og = nb * 64 + tr;

    #pragma unroll 1
    for (int s = 0; s < nsup; ++s) {
        const int sup = sup0 + s;

        // ---- per-wave unique weights: issue first (HBM, overlaps staging) ----
        intx4 br[8];
        #pragma unroll
        for (int st = 0; st < 8; ++st)
            br[st] = __builtin_nontemporal_load((const intx4*)(bp0 + s * 128 + st * 16));

        // ---- staging loads into VGPRs (coalesced, L2-hot) ----
        intx4 xtmp[8];
        const intx4* xsrc = xp + sup * 512;
        #pragma unroll
        for (int i = 0; i < 8; ++i) {
            const int idx = i * 256 + tid;
            xtmp[i] = xsrc[(idx >> 9) * 22016 + (idx & 511)];
        }
        intx4 sct0, sct1;
        float dtmp = 0.0f;
        if (w == 0) {
            sct0 = *(const intx4*)(scales + og * SB_ROW + sup * 8);
            sct1 = *(const intx4*)(scales + og * SB_ROW + sup * 8 + 4);
        } else if (w == 1) {
            sct0 = *(const intx4*)(mins + og * SB_ROW + sup * 8);
            sct1 = *(const intx4*)(mins + og * SB_ROW + sup * 8 + 4);
        } else if (w == 2) {
            dtmp = dd[og * NSUP + sup];
        } else {
            dtmp = dmn_g[og * NSUP + sup];
        }

        // ---- commit to LDS ----
        if (s > 0) __syncthreads();           // previous sup's readers done
        #pragma unroll
        for (int i = 0; i < 8; ++i)
            xfs[i * 256 + tid] = xtmp[i];
        if (w == 0) {
            *(intx4*)&scs[tr * 8]     = sct0;
            *(intx4*)&scs[tr * 8 + 4] = sct1;
        } else if (w == 1) {
            *(intx4*)&mns[tr * 8]     = sct0;
            *(intx4*)&mns[tr * 8 + 4] = sct1;
        } else if (w == 2) {
            dsx[tr] = dtmp;
        } else {
            dmx[tr] = dtmp;
        }
        __syncthreads();

        // ---- per-lane dequant constants from LDS ----
        const float dv   = dsx[r];
        const float dmv  = dmx[r];
        const float A945 = dv * (1.0f / 945.0f);
        const float A63  = dv * (1.0f / 63.0f);
        const intx4 s0 = *(const intx4*)&scs[r * 8];
        const intx4 s1 = *(const intx4*)&scs[r * 8 + 4];
        const intx4 m0 = *(const intx4*)&mns[r * 8];
        const intx4 m1 = *(const intx4*)&mns[r * 8 + 4];

        // ---- 8 K-steps: ds_read fragments + dequant + MFMA ----
        #pragma unroll
        for (int st = 0; st < 8; ++st) {
            const int scv = (st < 4) ? s0[st & 3] : s1[st & 3];
            const int mnv = (st < 4) ? m0[st & 3] : m1[st & 3];
            const float A = A945 * (float)scv;
            const float B = fmaf(A63, (float)mnv, dmv);
            const int v0 = br[st].x, v1 = br[st].y, v2 = br[st].z, v3 = br[st].w;
            union { intx4 i; short8 s8; } uw;
            uw.i.x = pack_bf16(fmaf((float)(v0 & 15), A, B), fmaf((float)(v0 >> 4), A, B));
            uw.i.y = pack_bf16(fmaf((float)(v1 & 15), A, B), fmaf((float)(v1 >> 4), A, B));
            uw.i.z = pack_bf16(fmaf((float)(v2 & 15), A, B), fmaf((float)(v2 >> 4), A, B));
            uw.i.w = pack_bf16(fmaf((float)(v3 & 15), A, B), fmaf((float)(v3 >> 4), A, B));

            union { intx4 i; short8 s8; } u0, u1, u2, u3;
            u0.i = xfs[0 * 512 + st * 64 + l];
            u1.i = xfs[1 * 512 + st * 64 + l];
            u2.i = xfs[2 * 512 + st * 64 + l];
            u3.i = xfs[3 * 512 + st * 64 + l];
            acc[0] = __builtin_amdgcn_mfma_f32_16x16x32_bf16(u0.s8, uw.s8, acc[0], 0, 0, 0);
            acc[1] = __builtin_amdgcn_mfma_f32_16x16x32_bf16(u1.s8, uw.s8, acc[1], 0, 0, 0);
            acc[2] = __builtin_amdgcn_mfma_f32_16x16x32_bf16(u2.s8, uw.s8, acc[2], 0, 0, 0);
            acc[3] = __builtin_amdgcn_mfma_f32_16x16x32_bf16(u3.s8, uw.s8, acc[3], 0, 0, 0);
        }
    }

    // ---- epilogue: D col = lane&15 = n (out-feature o), row = hi*4+rr = m ----
    if (USE_PART) {
        float* pbase = part + (size_t)ks * (BATCH * OUT_F) + o;
        #pragma unroll
        for (int mt = 0; mt < 4; ++mt) {
            #pragma unroll
            for (int rr = 0; rr < 4; ++rr)
                pbase[(mt * 16 + hi * 4 + rr) * OUT_F] = acc[mt][rr];
        }
    } else {
        #pragma unroll
        for (int mt = 0; mt < 4; ++mt) {
            #pragma unroll
            for (int rr = 0; rr < 4; ++rr)
                atomicAdd(out + (mt * 16 + hi * 4 + rr) * OUT_F + o, acc[mt][rr]);
        }
    }
}

extern "C" void kernel_launch(void* const* d_in, const int* in_sizes, int n_in,
                              void* d_out, int out_size, void* d_ws, size_t ws_size,
                              hipStream_t stream) {
    (void)in_sizes; (void)n_in; (void)out_size;
    const float* x      = (const float*)d_in[0];
    const int*   packed = (const int*)d_in[1];
    const float* d      = (const float*)d_in[2];
    const float* dmin   = (const float*)d_in[3];
    const int*   scales = (const int*)d_in[4];
    const int*   mins   = (const int*)d_in[5];
    const float* bias   = (const float*)d_in[6];
    float* out = (float*)d_out;

    const bool has_part = ws_size >= (size_t)WS_FULL;
    intx4* xp   = (intx4*)d_ws;
    float* part = (float*)((char*)d_ws + XP_BYTES);

    xprep_kernel<<<344, 256, 0, stream>>>(x, xp);

    if (has_part) {
        qlin_main<true><<<64 * NKS, 256, 0, stream>>>(
            xp, packed, d, dmin, scales, mins, part, out);
        reduce_kernel<<<(BATCH * OUT_F) / 256, 256, 0, stream>>>(part, bias, out);
    } else {
        init_out_kernel<<<(BATCH * OUT_F) / 256, 256, 0, stream>>>(bias, out);
        qlin_main<false><<<64 * NKS, 256, 0, stream>>>(
            xp, packed, d, dmin, scales, mins, part, out);
    }
}